// Round 7
// baseline (33461.618 us; speedup 1.0000x reference)
//
#include <hip/hip_runtime.h>
#include <hip/hip_bf16.h>

typedef __attribute__((ext_vector_type(8))) short short8;   // 8 x bf16 (4 VGPRs)
typedef __attribute__((ext_vector_type(4))) float floatx4;  // MFMA C/D

#define B_ 128
#define T_ 1024
#define H_ 256
#define G_ 1024   // 4*H

__device__ __forceinline__ float sigmoidf_(float x) {
    x = fminf(fmaxf(x, -30.f), 30.f);
    return 1.0f / (1.0f + __expf(-x));
}
__device__ __forceinline__ float tanhf_(float x) {
    x = fminf(fmaxf(x, -15.f), 15.f);
    float e = __expf(2.0f * x);
    return 1.0f - 2.0f / (e + 1.0f);
}
__device__ __forceinline__ unsigned short f2bu(float x) {
    __hip_bfloat16 b = __float2bfloat16(x);
    return *reinterpret_cast<unsigned short*>(&b);
}

// ---------------------------------------------------------------------------
// GEMM, f32 in / f32 out, bf16 MFMA internally.
// C[rm,n] = sum_k A[rm,k]*Wt[n,k] + b1[n] (+ b2[n])
// rm: i1 = rm >> d2shift, i2 = rm & mask; A addr = A + i1*sa1 + i2*sa2 + k
// C addr = C + i1*sc1 + i2*sc2 + n.  M = gridDim.x*64, N = gridDim.y*64.
// K % 32 == 0. Block = 256 threads. (m92-lineage verified MFMA core.)
// ---------------------------------------------------------------------------
__global__ __launch_bounds__(256) void gemm_bias_f32(
    const float* __restrict__ A,
    const float* __restrict__ Wt,        // [N][K] row-major
    const float* __restrict__ bias1,
    const float* __restrict__ bias2,     // nullable
    float* __restrict__ C,
    int d2shift, long sa1, long sa2, long sc1, long sc2, int K)
{
    __shared__ __hip_bfloat16 a_tile[64][40];  // 32 K + 8 pad
    __shared__ __hip_bfloat16 b_tile[64][40];

    const int tid  = threadIdx.x;
    const int wave = tid >> 6;
    const int lane = tid & 63;
    const int quad = lane >> 4;
    const int l16  = lane & 15;

    const int bm = blockIdx.x * 64;
    const int bn = blockIdx.y * 64;
    const int mask = (1 << d2shift) - 1;

    const int lr  = tid >> 2;   // staging row 0..63
    const int seg = tid & 3;    // 8-element segment

    const int grow = bm + lr;
    const float* abase =
        A + (long)(grow >> d2shift) * sa1 + (long)(grow & mask) * sa2 + seg * 8;
    const float* bbase = Wt + (long)(bn + lr) * K + seg * 8;

    floatx4 acc[4];
    #pragma unroll
    for (int nt = 0; nt < 4; ++nt) acc[nt] = (floatx4){0.f, 0.f, 0.f, 0.f};

    for (int kk = 0; kk < K; kk += 32) {
        float4 a0 = *(const float4*)(abase + kk);
        float4 a1 = *(const float4*)(abase + kk + 4);
        float4 b0 = *(const float4*)(bbase + kk);
        float4 b1 = *(const float4*)(bbase + kk + 4);
        uint4 ap, bp;
        ap.x = f2bu(a0.x) | ((unsigned)f2bu(a0.y) << 16);
        ap.y = f2bu(a0.z) | ((unsigned)f2bu(a0.w) << 16);
        ap.z = f2bu(a1.x) | ((unsigned)f2bu(a1.y) << 16);
        ap.w = f2bu(a1.z) | ((unsigned)f2bu(a1.w) << 16);
        bp.x = f2bu(b0.x) | ((unsigned)f2bu(b0.y) << 16);
        bp.y = f2bu(b0.z) | ((unsigned)f2bu(b0.w) << 16);
        bp.z = f2bu(b1.x) | ((unsigned)f2bu(b1.y) << 16);
        bp.w = f2bu(b1.z) | ((unsigned)f2bu(b1.w) << 16);
        __syncthreads();  // prior iter's LDS reads done
        *(uint4*)&a_tile[lr][seg * 8] = ap;
        *(uint4*)&b_tile[lr][seg * 8] = bp;
        __syncthreads();
        short8 af = *(const short8*)&a_tile[wave * 16 + l16][quad * 8];
        #pragma unroll
        for (int nt = 0; nt < 4; ++nt) {
            short8 bf = *(const short8*)&b_tile[nt * 16 + l16][quad * 8];
            acc[nt] = __builtin_amdgcn_mfma_f32_16x16x32_bf16(af, bf, acc[nt], 0, 0, 0);
        }
    }

    // epilogue: C/D layout col = lane&15, row = quad*4 + r
    #pragma unroll
    for (int nt = 0; nt < 4; ++nt) {
        const int col = bn + nt * 16 + l16;
        float bsum = bias1[col];
        if (bias2) bsum += bias2[col];
        #pragma unroll
        for (int r = 0; r < 4; ++r) {
            const int rm = bm + wave * 16 + quad * 4 + r;
            const long off = (long)(rm >> d2shift) * sc1 + (long)(rm & mask) * sc2;
            C[off + col] = acc[nt][r] + bsum;
        }
    }
}

// ---------------------------------------------------------------------------
// w_hh [G][H] f32 -> wt [H][G] f32 (so recurrence weight reads are coalesced)
// ---------------------------------------------------------------------------
__global__ __launch_bounds__(256) void transpose_whh(
    const float* __restrict__ src,   // [G][H]
    float* __restrict__ dst)         // [H][G]
{
    const int i = blockIdx.x * 256 + threadIdx.x;  // < G*H
    const int g = i >> 8;     // / H
    const int k = i & 255;    // % H
    dst[k * G_ + g] = src[i];
}

// ---------------------------------------------------------------------------
// Simple all-f32 LSTM recurrence over one chunk of Tc steps.
// Grid = 64 blocks (2 batch rows each), block = 512 threads:
// thread = (row = tid>>8, hidden unit j = tid&255). h in LDS (f32).
// Each thread: 4 gate dot-products of length 256, f32 accumulate.
// ---------------------------------------------------------------------------
__global__ __launch_bounds__(512) void lstm_simple(
    const float* __restrict__ xg,     // [Tc][B][G] (incl. both biases)
    const float* __restrict__ wt,     // [H][G] = w_hh^T
    float* __restrict__ h_seq,        // [Tc][B][H]
    const float* __restrict__ h_in,   // [B][H]
    const float* __restrict__ c_in,   // [B][H]
    float* __restrict__ h_out,        // [B][H]
    float* __restrict__ c_out,        // [B][H]
    float* __restrict__ c_fin,        // nullable [B][H]
    int Tc, int init)
{
    const int row = threadIdx.x >> 8;          // 0..1
    const int j   = threadIdx.x & 255;         // hidden unit
    const int b   = blockIdx.x * 2 + row;      // batch row

    __shared__ float h_sh[2][H_];

    float h0 = 0.f, c = 0.f;
    if (!init) {
        h0 = h_in[(long)b * H_ + j];
        c  = c_in[(long)b * H_ + j];
    }
    h_sh[row][j] = h0;

    for (int t = 0; t < Tc; ++t) {
        __syncthreads();  // h_sh(t) writes visible

        const float* xgt = xg + (long)t * (B_ * G_) + (long)b * G_;
        float ai = xgt[j];
        float af = xgt[256 + j];
        float ag = xgt[512 + j];
        float ao = xgt[768 + j];

        #pragma unroll 4
        for (int k = 0; k < H_; ++k) {
            const float hk = h_sh[row][k];          // broadcast (free)
            const float* wr = wt + (long)k * G_;
            ai = fmaf(hk, wr[      j], ai);
            af = fmaf(hk, wr[256 + j], af);
            ag = fmaf(hk, wr[512 + j], ag);
            ao = fmaf(hk, wr[768 + j], ao);
        }

        const float iv = sigmoidf_(ai);
        const float fv = sigmoidf_(af);
        const float gv = tanhf_(ag);
        const float ov = sigmoidf_(ao);
        c = fv * c + iv * gv;
        const float hv = ov * tanhf_(c);

        __syncthreads();  // all reads of h_sh(t) done before overwrite
        h_sh[row][j] = hv;
        h_seq[(long)t * (B_ * H_) + (long)b * H_ + j] = hv;
    }

    h_out[(long)b * H_ + j] = h_sh[row][j];
    c_out[(long)b * H_ + j] = c;
    if (c_fin) c_fin[(long)b * H_ + j] = c;
}

// ---------------------------------------------------------------------------
extern "C" void kernel_launch(void* const* d_in, const int* in_sizes, int n_in,
                              void* d_out, int out_size, void* d_ws, size_t ws_size,
                              hipStream_t stream)
{
    const float* x     = (const float*)d_in[0];   // [B][T][128]
    const float* w_ih0 = (const float*)d_in[1];   // [1024][128]
    const float* w_hh0 = (const float*)d_in[2];   // [1024][256]
    const float* b_ih0 = (const float*)d_in[3];
    const float* b_hh0 = (const float*)d_in[4];
    const float* w_ih1 = (const float*)d_in[5];   // [1024][256]
    const float* w_hh1 = (const float*)d_in[6];   // [1024][256]
    const float* b_ih1 = (const float*)d_in[7];
    const float* b_hh1 = (const float*)d_in[8];
    const float* w_lin = (const float*)d_in[9];   // [128][256]
    const float* b_lin = (const float*)d_in[10];

    float* out  = (float*)d_out;                   // [B][T][128]
    float* hfin = out + (size_t)B_ * T_ * 128;     // [2][B][H]
    float* cfin = hfin + 2 * (B_ * H_);            // [2][B][H]

    // ---- fixed workspace: wt0/wt1 (f32) + state carry ≈ 2.5 MB ----
    char* p = (char*)d_ws;
    float* wt0  = (float*)p;  p += (size_t)G_ * H_ * 4;   // 1 MB
    float* wt1  = (float*)p;  p += (size_t)G_ * H_ * 4;   // 1 MB
    float* h0st = (float*)p;  p += 131072;                // [B][H] f32
    float* h1st = (float*)p;  p += 131072;
    float* c0st = (float*)p;  p += 131072;
    float* c1st = (float*)p;  p += 131072;
    const size_t fixed = (size_t)(p - (char*)d_ws);

    // per chunk: xg Tc*524288 B + h0c/h1c Tc*131072 B each = Tc*786432 B
    int Tc = 1024;
    while (Tc > 1 && fixed + (size_t)Tc * 786432u > ws_size) Tc >>= 1;
    const int nc = T_ / Tc;
    const int tshift = __builtin_ctz((unsigned)Tc);

    float* xgc = (float*)p;  p += (size_t)Tc * 524288;    // [Tc][B][G]
    float* h0c = (float*)p;  p += (size_t)Tc * 131072;    // [Tc][B][H]
    float* h1c = (float*)p;                               // [Tc][B][H]

    // ---- transpose both recurrence weight matrices once ----
    transpose_whh<<<dim3(1024), dim3(256), 0, stream>>>(w_hh0, wt0);
    transpose_whh<<<dim3(1024), dim3(256), 0, stream>>>(w_hh1, wt1);

    // ---- chunked pipeline ----
    for (int i = 0; i < nc; ++i) {
        const long t0   = (long)i * Tc;
        const int  init = (i == 0);
        const int  last = (i == nc - 1);

        // xg0[tl*B+b, g] = x[b, t0+tl, :] . w_ih0[g,:] + b_ih0 + b_hh0
        gemm_bias_f32<<<dim3(2 * Tc, 16), dim3(256), 0, stream>>>(
            x + t0 * 128, w_ih0, b_ih0, b_hh0, xgc,
            7, 128L, 131072L, 131072L, 1024L, 128);

        lstm_simple<<<dim3(64), dim3(512), 0, stream>>>(
            xgc, wt0, h0c, h0st, c0st,
            last ? hfin : h0st, c0st, last ? cfin : (float*)nullptr,
            Tc, init);

        // xg1[tl*B+b, g] = h0c[tl, b, :] . w_ih1[g,:] + b_ih1 + b_hh1
        gemm_bias_f32<<<dim3(2 * Tc, 16), dim3(256), 0, stream>>>(
            h0c, w_ih1, b_ih1, b_hh1, xgc,
            7, 32768L, 256L, 131072L, 1024L, 256);

        lstm_simple<<<dim3(64), dim3(512), 0, stream>>>(
            xgc, wt1, h1c, h1st, c1st,
            last ? hfin + B_ * H_ : h1st, c1st,
            last ? cfin + B_ * H_ : (float*)nullptr,
            Tc, init);

        // out[b, t0+tl, o] = h1c[tl, b, :] . w_lin[o,:] + b_lin ; rm = b*Tc + tl
        gemm_bias_f32<<<dim3(2 * Tc, 2), dim3(256), 0, stream>>>(
            h1c, w_lin, b_lin, (const float*)nullptr, out + t0 * 128,
            tshift, 256L, 32768L, 131072L, 128L, 256);
    }
}